// Round 2
// baseline (3230.059 us; speedup 1.0000x reference)
//
#include <hip/hip_runtime.h>
#include <math.h>

#define S_LEN 2048
#define D_DIM 64
#define NHEAD 16
#define NBH 32
#define QBLK 16
#define KT 64
#define LG_STRIDE 2052   // 2052%32==4 -> lg[r][k] banks (4r+k)%32, conflict-free for 4-row reads; 2052*4 bytes is 16B-aligned
#define SMEM_FLOATS (QBLK*LG_STRIDE + KT*D_DIM + 16)
#define SMEM_BYTES  (SMEM_FLOATS*4)

__global__ __launch_bounds__(256, 1)
void attn_fp32_kernel(const float* __restrict__ q, const float* __restrict__ kmat,
                      const float* __restrict__ vmat, const float* __restrict__ mask,
                      float* __restrict__ out, float* __restrict__ wout)
{
    extern __shared__ float smem[];
    float* lg   = smem;                      // [QBLK][LG_STRIDE]: logits -> exp values
    float* kst  = smem + QBLK*LG_STRIDE;     // [KT][D]: K^T staging, then V staging
    float* invs = kst + KT*D_DIM;            // [QBLK]: per-row 1/sum

    const int t  = threadIdx.x;
    const int bh = blockIdx.y;
    const int b  = bh / NHEAD;
    const int qb = blockIdx.x * QBLK;

    const int r  = t >> 4;          // owned q-row (0..15); wave-local r spans 4 values
    const int g  = t & 15;          // sub-group within row
    const int c0 = g * 4;           // key offset group for QK^T

    const int sk_key = t >> 2;        // staging: key row 0..63
    const int sk_d0  = (t & 3) * 16;  // staging: d offset

    // ---- q row into registers (64 VGPRs) ----
    float qreg[D_DIM];
    {
        const float4* qrow = reinterpret_cast<const float4*>(q + ((size_t)bh*S_LEN + qb + r)*D_DIM);
        #pragma unroll
        for (int i = 0; i < D_DIM/4; ++i) {
            float4 f = qrow[i];
            qreg[4*i+0]=f.x; qreg[4*i+1]=f.y; qreg[4*i+2]=f.z; qreg[4*i+3]=f.w;
        }
    }

    // ---- phase A: logits = QK^T * 0.125 + mask * -1e9  -> lg ----
    // software pipeline: prefetch next K tile into regs during compute; the
    // loads drain at the next barrier's vmcnt(0) (issuing BEFORE a barrier is
    // useless on gfx950 -- the barrier drains vmcnt to 0).
    float4 pk[4];
    {
        const float4* krow = reinterpret_cast<const float4*>(
            kmat + ((size_t)bh*S_LEN + sk_key)*D_DIM + sk_d0);
        #pragma unroll
        for (int j = 0; j < 4; ++j) pk[j] = krow[j];
    }
    for (int kb = 0; kb < S_LEN; kb += KT) {
        __syncthreads();   // previous tile's kst reads done; prefetched loads drained
        {   // stage K tile transposed: kst[d][key]
            #pragma unroll
            for (int j = 0; j < 4; ++j) {
                float4 f = pk[j];
                int d0 = sk_d0 + 4*j;
                kst[(d0+0)*KT + sk_key] = f.x;
                kst[(d0+1)*KT + sk_key] = f.y;
                kst[(d0+2)*KT + sk_key] = f.z;
                kst[(d0+3)*KT + sk_key] = f.w;
            }
        }
        __syncthreads();
        if (kb + KT < S_LEN) {   // issue next-tile loads; they fly during compute
            const float4* krow = reinterpret_cast<const float4*>(
                kmat + ((size_t)bh*S_LEN + kb + KT + sk_key)*D_DIM + sk_d0);
            #pragma unroll
            for (int j = 0; j < 4; ++j) pk[j] = krow[j];
        }
        float4 mk = *reinterpret_cast<const float4*>(   // issue early, used after d-loop
            mask + ((size_t)b*S_LEN + qb + r)*S_LEN + kb + c0);
        float a0=0.f, a1=0.f, a2=0.f, a3=0.f;
        #pragma unroll 16
        for (int d = 0; d < D_DIM; ++d) {
            float4 kv = *reinterpret_cast<const float4*>(&kst[d*KT + c0]);
            float qd = qreg[d];
            a0 = fmaf(qd, kv.x, a0);
            a1 = fmaf(qd, kv.y, a1);
            a2 = fmaf(qd, kv.z, a2);
            a3 = fmaf(qd, kv.w, a3);
        }
        float* dst = &lg[r*LG_STRIDE + kb + c0];
        dst[0] = fmaf(mk.x, -1e9f, a0*0.125f);
        dst[1] = fmaf(mk.y, -1e9f, a1*0.125f);
        dst[2] = fmaf(mk.z, -1e9f, a2*0.125f);
        dst[3] = fmaf(mk.w, -1e9f, a3*0.125f);
    }
    __syncthreads();

    // ---- phase B: row softmax (16 lanes per row, 128 floats each) ----
    {
        float4* seg = reinterpret_cast<float4*>(&lg[r*LG_STRIDE + g*128]);
        float m = -3.0e38f;
        #pragma unroll 8
        for (int i = 0; i < 32; ++i) {
            float4 x = seg[i];
            m = fmaxf(m, fmaxf(fmaxf(x.x, x.y), fmaxf(x.z, x.w)));
        }
        #pragma unroll
        for (int o = 1; o < 16; o <<= 1) m = fmaxf(m, __shfl_xor(m, o));
        float ssum = 0.f;
        #pragma unroll 8
        for (int i = 0; i < 32; ++i) {
            float4 x = seg[i];
            x.x = __expf(x.x - m);
            x.y = __expf(x.y - m);
            x.z = __expf(x.z - m);
            x.w = __expf(x.w - m);
            ssum += (x.x + x.y) + (x.z + x.w);
            seg[i] = x;   // store unnormalized exp back
        }
        #pragma unroll
        for (int o = 1; o < 16; o <<= 1) ssum += __shfl_xor(ssum, o);
        if (g == 0) invs[r] = 1.f / ssum;
    }
    __syncthreads();

    // prefetch first V tile before the weights write so HBM latency hides
    // under phase C's streaming stores
    float4 pv[4];
    {
        const float4* vrow = reinterpret_cast<const float4*>(
            vmat + ((size_t)bh*S_LEN + sk_key)*D_DIM + sk_d0);
        #pragma unroll
        for (int j = 0; j < 4; ++j) pv[j] = vrow[j];
    }

    // ---- phase C: write normalized weights (coalesced float4) ----
    #pragma unroll 4
    for (int p = 0; p < 32; ++p) {
        int idx = p*256 + t;
        int row = idx >> 9;      // 512 float4 per row
        int cc  = idx & 511;
        float4 e4 = *reinterpret_cast<const float4*>(&lg[row*LG_STRIDE + cc*4]);
        float is = invs[row];
        float4 w4 = make_float4(e4.x*is, e4.y*is, e4.z*is, e4.w*is);
        reinterpret_cast<float4*>(wout + ((size_t)bh*S_LEN + qb + row)*S_LEN)[cc] = w4;
    }

    // ---- phase D: out = (exp @ V) * inv_sum ----
    const int dg4 = g * 4;
    float4 acc = make_float4(0.f, 0.f, 0.f, 0.f);
    for (int kb = 0; kb < S_LEN; kb += KT) {
        __syncthreads();   // previous tile's kst reads done; prefetched loads drained
        {   // stage V tile: kst[key][d] (no transpose)
            float4* vdst = reinterpret_cast<float4*>(&kst[sk_key*D_DIM + sk_d0]);
            #pragma unroll
            for (int j = 0; j < 4; ++j) vdst[j] = pv[j];
        }
        __syncthreads();
        if (kb + KT < S_LEN) {   // issue next-tile loads; they fly during compute
            const float4* vrow = reinterpret_cast<const float4*>(
                vmat + ((size_t)bh*S_LEN + kb + KT + sk_key)*D_DIM + sk_d0);
            #pragma unroll
            for (int j = 0; j < 4; ++j) pv[j] = vrow[j];
        }
        const float* wrow = &lg[r*LG_STRIDE + kb];
        #pragma unroll 8
        for (int kk = 0; kk < KT; ++kk) {
            float w = wrow[kk];                    // wave-uniform per 16 lanes: broadcast
            float4 vv = *reinterpret_cast<const float4*>(&kst[kk*D_DIM + dg4]);
            acc.x = fmaf(w, vv.x, acc.x);
            acc.y = fmaf(w, vv.y, acc.y);
            acc.z = fmaf(w, vv.z, acc.z);
            acc.w = fmaf(w, vv.w, acc.w);
        }
    }
    {
        float is = invs[r];
        float4 o4 = make_float4(acc.x*is, acc.y*is, acc.z*is, acc.w*is);
        reinterpret_cast<float4*>(out + ((size_t)bh*S_LEN + qb + r)*D_DIM)[g] = o4;
    }
}

extern "C" void kernel_launch(void* const* d_in, const int* in_sizes, int n_in,
                              void* d_out, int out_size, void* d_ws, size_t ws_size,
                              hipStream_t stream) {
    const float* q = (const float*)d_in[0];
    const float* k = (const float*)d_in[1];
    const float* v = (const float*)d_in[2];
    const float* m = (const float*)d_in[3];
    float* out  = (float*)d_out;
    float* wout = out + (size_t)NBH * S_LEN * D_DIM;   // tuple: [out | weights]

    hipFuncSetAttribute(reinterpret_cast<const void*>(attn_fp32_kernel),
                        hipFuncAttributeMaxDynamicSharedMemorySize, SMEM_BYTES);
    dim3 grid(S_LEN/QBLK, NBH);
    attn_fp32_kernel<<<grid, dim3(256,1,1), SMEM_BYTES, stream>>>(q, k, v, m, out, wout);
}

// Round 3
// 810.156 us; speedup vs baseline: 3.9870x; 3.9870x over previous
//
#include <hip/hip_runtime.h>
#include <hip/hip_bf16.h>
#include <math.h>

#define S_LEN 2048
#define D_DIM 64
#define NHEAD 16
#define NBH   32
#define QBLK  64      // q-rows per WG (4 waves x 16)
#define KT    64      // keys per tile
#define NT    32      // S_LEN / KT
#define KST   76      // bf16 elems per LDS tile row (stride): 38 words -> 6r banks, conflict-free frags
#define QST   68      // f32 stride for Q staging

typedef __attribute__((ext_vector_type(4))) float f32x4;
typedef __attribute__((ext_vector_type(4))) short s16x4;
typedef __attribute__((ext_vector_type(8))) short s16x8;

union Frag { s16x8 v; s16x4 h[2]; };

#define SZ_TILE (64 * KST * 2)          // 9728 B per bf16 tile
#define OFF_KHI 0
#define OFF_KLO (SZ_TILE)
#define OFF_V   (2 * SZ_TILE)
#define OFF_W   (3 * SZ_TILE)
#define SZ_W    (16 * KST * 2)          // 2432 B per-wave P tile
#define LDS_BYTES (OFF_W + 4 * SZ_W)    // 38912 B -> 3-4 WGs/CU

static __device__ __forceinline__ unsigned short f2bf(float x) {
    __hip_bfloat16 h = __float2bfloat16(x);
    return *reinterpret_cast<unsigned short*>(&h);
}
static __device__ __forceinline__ float bf2f(unsigned short u) {
    return __uint_as_float(((unsigned int)u) << 16);
}

__global__ __launch_bounds__(256, 3)
void attn_mfma_kernel(const float* __restrict__ q, const float* __restrict__ kmat,
                      const float* __restrict__ vmat, const float* __restrict__ mask,
                      float* __restrict__ out, float* __restrict__ wout)
{
    extern __shared__ char smem[];
    unsigned short* khi = (unsigned short*)(smem + OFF_KHI);
    unsigned short* klo = (unsigned short*)(smem + OFF_KLO);
    unsigned short* vld = (unsigned short*)(smem + OFF_V);
    float* qlds = (float*)smem;          // aliases khi+klo region (17408 <= 19456)

    const int t    = threadIdx.x;
    const int wv   = t >> 6;
    const int lane = t & 63;
    const int g    = lane >> 4;          // 16-lane group (MFMA k/row group)
    const int c    = lane & 15;          // col-in-frag
    unsigned short* wlds = (unsigned short*)(smem + OFF_W + wv * SZ_W);

    // XCD-aware bijective swizzle: 1024 WGs, XCD x gets newid x*128..x*128+127
    const int bid   = blockIdx.x;
    const int newid = ((bid & 7) << 7) + (bid >> 3);
    const int bh    = newid >> 5;        // same bh -> same XCD chunk (K/V L2 reuse)
    const int b     = bh >> 4;
    const int qb    = (newid & 31) * QBLK;

    const int skey = t >> 2;             // staging: key row 0..63
    const int sd0  = (t & 3) << 4;       // staging: d offset

    const float* Qg = q    + ((size_t)bh * S_LEN + qb) * D_DIM;
    const float* Kg = kmat + (size_t)bh * S_LEN * D_DIM;
    const float* Vg = vmat + (size_t)bh * S_LEN * D_DIM;

    // ---- stage Q (fp32, coalesced) ----
    {
        const float4* src = (const float4*)(Qg + skey * D_DIM + sd0);
        #pragma unroll
        for (int j = 0; j < 4; ++j)
            *(float4*)&qlds[skey * QST + sd0 + 4 * j] = src[j];
    }
    __syncthreads();
    // ---- extract Q frags: A[row=c][k = 4g + j + 16h + 32f], split hi/lo ----
    Frag qhi[2], qlo[2];
    {
        const int qrow = wv * 16 + c;
        #pragma unroll
        for (int f = 0; f < 2; ++f)
            #pragma unroll
            for (int h = 0; h < 2; ++h) {
                float4 x = *(const float4*)&qlds[qrow * QST + 4 * g + 16 * h + 32 * f];
                unsigned short h0 = f2bf(x.x), h1 = f2bf(x.y), h2 = f2bf(x.z), h3 = f2bf(x.w);
                s16x4 hv = { (short)h0, (short)h1, (short)h2, (short)h3 };
                qhi[f].h[h] = hv;
                s16x4 lv = { (short)f2bf(x.x - bf2f(h0)), (short)f2bf(x.y - bf2f(h1)),
                             (short)f2bf(x.z - bf2f(h2)), (short)f2bf(x.w - bf2f(h3)) };
                qlo[f].h[h] = lv;
            }
    }
    __syncthreads();

    // per-lane row pointers (D-frag rows 4g+i)
    const float* mrow[4];
    float*       wrow[4];
    #pragma unroll
    for (int i = 0; i < 4; ++i) {
        const int row = qb + wv * 16 + 4 * g + i;
        mrow[i] = mask + ((size_t)b  * S_LEN + row) * S_LEN;
        wrow[i] = wout + ((size_t)bh * S_LEN + row) * S_LEN;
    }

    // ================= pass 1: Z = sum exp(logits)  (bf16-hi only) =================
    float Z[4] = {0.f, 0.f, 0.f, 0.f};
    for (int kt = 0; kt < NT; ++kt) {
        __syncthreads();
        {   // stage K tile as bf16-hi
            const float4* ks = (const float4*)(Kg + (size_t)(kt * KT + skey) * D_DIM + sd0);
            #pragma unroll
            for (int j = 0; j < 4; ++j) {
                float4 x = ks[j];
                uint2 hp;
                hp.x = (unsigned)f2bf(x.x) | ((unsigned)f2bf(x.y) << 16);
                hp.y = (unsigned)f2bf(x.z) | ((unsigned)f2bf(x.w) << 16);
                *(uint2*)&khi[skey * KST + sd0 + 4 * j] = hp;
            }
        }
        __syncthreads();
        #pragma unroll
        for (int kbi = 0; kbi < 4; ++kbi) {
            const int key0 = kbi * 16;
            Frag kf[2];
            const unsigned short* kbase = &khi[(key0 + c) * KST + 4 * g];
            #pragma unroll
            for (int f = 0; f < 2; ++f) {
                kf[f].h[0] = *(const s16x4*)&kbase[32 * f];
                kf[f].h[1] = *(const s16x4*)&kbase[32 * f + 16];
            }
            f32x4 acc = {0.f, 0.f, 0.f, 0.f};
            acc = __builtin_amdgcn_mfma_f32_16x16x32_bf16(qhi[0].v, kf[0].v, acc, 0, 0, 0);
            acc = __builtin_amdgcn_mfma_f32_16x16x32_bf16(qhi[1].v, kf[1].v, acc, 0, 0, 0);
            const int gk = kt * KT + key0 + c;
            #pragma unroll
            for (int i = 0; i < 4; ++i) {
                float l = fmaf(mrow[i][gk], -1e9f, acc[i] * 0.125f);
                Z[i] += __expf(l);
            }
        }
    }
    float invZ[4];
    #pragma unroll
    for (int i = 0; i < 4; ++i) {
        float z = Z[i];
        #pragma unroll
        for (int o = 1; o < 16; o <<= 1) z += __shfl_xor(z, o);  // sum over 16 cols-lanes
        invZ[i] = 1.f / z;
    }

    // ========= pass 2: recompute (split bf16 = fp32-accurate), weights + PV =========
    f32x4 oacc[4] = {{0,0,0,0},{0,0,0,0},{0,0,0,0},{0,0,0,0}};
    for (int kt = 0; kt < NT; ++kt) {
        __syncthreads();
        {   // stage K hi+lo and V (bf16)
            const float4* ks = (const float4*)(Kg + (size_t)(kt * KT + skey) * D_DIM + sd0);
            const float4* vs = (const float4*)(Vg + (size_t)(kt * KT + skey) * D_DIM + sd0);
            #pragma unroll
            for (int j = 0; j < 4; ++j) {
                float4 x = ks[j];
                unsigned short h0 = f2bf(x.x), h1 = f2bf(x.y), h2 = f2bf(x.z), h3 = f2bf(x.w);
                uint2 hp; hp.x = (unsigned)h0 | ((unsigned)h1 << 16);
                          hp.y = (unsigned)h2 | ((unsigned)h3 << 16);
                uint2 lp;
                lp.x = (unsigned)f2bf(x.x - bf2f(h0)) | ((unsigned)f2bf(x.y - bf2f(h1)) << 16);
                lp.y = (unsigned)f2bf(x.z - bf2f(h2)) | ((unsigned)f2bf(x.w - bf2f(h3)) << 16);
                *(uint2*)&khi[skey * KST + sd0 + 4 * j] = hp;
                *(uint2*)&klo[skey * KST + sd0 + 4 * j] = lp;
                float4 y = vs[j];
                uint2 vp; vp.x = (unsigned)f2bf(y.x) | ((unsigned)f2bf(y.y) << 16);
                          vp.y = (unsigned)f2bf(y.z) | ((unsigned)f2bf(y.w) << 16);
                *(uint2*)&vld[skey * KST + sd0 + 4 * j] = vp;
            }
        }
        __syncthreads();
        #pragma unroll
        for (int kbi = 0; kbi < 4; ++kbi) {
            const int key0 = kbi * 16;
            Frag kh[2], kl[2];
            const unsigned short* kbh = &khi[(key0 + c) * KST + 4 * g];
            const unsigned short* kbl = &klo[(key0 + c) * KST + 4 * g];
            #pragma unroll
            for (int f = 0; f < 2; ++f) {
                kh[f].h[0] = *(const s16x4*)&kbh[32 * f];
                kh[f].h[1] = *(const s16x4*)&kbh[32 * f + 16];
                kl[f].h[0] = *(const s16x4*)&kbl[32 * f];
                kl[f].h[1] = *(const s16x4*)&kbl[32 * f + 16];
            }
            f32x4 acc = {0.f, 0.f, 0.f, 0.f};
            acc = __builtin_amdgcn_mfma_f32_16x16x32_bf16(qhi[0].v, kh[0].v, acc, 0, 0, 0);
            acc = __builtin_amdgcn_mfma_f32_16x16x32_bf16(qhi[1].v, kh[1].v, acc, 0, 0, 0);
            acc = __builtin_amdgcn_mfma_f32_16x16x32_bf16(qhi[0].v, kl[0].v, acc, 0, 0, 0);
            acc = __builtin_amdgcn_mfma_f32_16x16x32_bf16(qhi[1].v, kl[1].v, acc, 0, 0, 0);
            acc = __builtin_amdgcn_mfma_f32_16x16x32_bf16(qlo[0].v, kh[0].v, acc, 0, 0, 0);
            acc = __builtin_amdgcn_mfma_f32_16x16x32_bf16(qlo[1].v, kh[1].v, acc, 0, 0, 0);
            const int gk = kt * KT + key0 + c;
            #pragma unroll
            for (int i = 0; i < 4; ++i) {
                float l = fmaf(mrow[i][gk], -1e9f, acc[i] * 0.125f);
                float w = __expf(l) * invZ[i];
                wrow[i][gk] = w;                                  // weights out (fp32)
                wlds[(4 * g + i) * KST + key0 + c] = f2bf(w);     // P -> A-frag layout
            }
        }
        // ---- PV: out += P(bf16) @ V(bf16) ----
        #pragma unroll
        for (int kc = 0; kc < 2; ++kc) {
            Frag pa;
            const unsigned short* pb = &wlds[c * KST + kc * 32 + 4 * g];
            pa.h[0] = *(const s16x4*)&pb[0];
            pa.h[1] = *(const s16x4*)&pb[16];
            #pragma unroll
            for (int n = 0; n < 4; ++n) {
                Frag vb;
                #pragma unroll
                for (int h = 0; h < 2; ++h) {
                    const unsigned short* vp = &vld[(kc * 32 + 16 * h + 4 * g) * KST + n * 16 + c];
                    s16x4 e = { (short)vp[0], (short)vp[KST], (short)vp[2 * KST], (short)vp[3 * KST] };
                    vb.h[h] = e;
                }
                oacc[n] = __builtin_amdgcn_mfma_f32_16x16x32_bf16(pa.v, vb.v, oacc[n], 0, 0, 0);
            }
        }
    }

    // ---- out store: lane holds out[4g+i][n*16+c] ----
    #pragma unroll
    for (int n = 0; n < 4; ++n)
        #pragma unroll
        for (int i = 0; i < 4; ++i)
            out[((size_t)bh * S_LEN + qb + wv * 16 + 4 * g + i) * D_DIM + n * 16 + c] = oacc[n][i];
}

extern "C" void kernel_launch(void* const* d_in, const int* in_sizes, int n_in,
                              void* d_out, int out_size, void* d_ws, size_t ws_size,
                              hipStream_t stream) {
    const float* q = (const float*)d_in[0];
    const float* k = (const float*)d_in[1];
    const float* v = (const float*)d_in[2];
    const float* m = (const float*)d_in[3];
    float* out  = (float*)d_out;
    float* wout = out + (size_t)NBH * S_LEN * D_DIM;   // tuple: [out | weights]

    dim3 grid(NBH * (S_LEN / QBLK));   // 1024
    attn_mfma_kernel<<<grid, dim3(256, 1, 1), LDS_BYTES, stream>>>(q, k, v, m, out, wout);
}